// Round 5
// baseline (3754.958 us; speedup 1.0000x reference)
//
#include <hip/hip_runtime.h>
#include <math.h>

#define HD 128
#define NBR 8
#define LSTEPS 64
#define TILE_B 32
#define HT_PAD 36     // 144B rows: float4-aligned; GEMM h-reads are wave-uniform broadcasts
#define PART_PAD 132  // 4-way on a tiny phase, negligible

// workspace layout (floats)
#define WPT_OFF   0        // w_hh permuted-transposed: [k][4*hh+q] = w_hh[q*128+hh][k]   (128*512)
#define WIPT_OFF  65536    // w_ih same layout                                            (128*512)
#define PP_OFF    131072   // P'' = w_emb@w_ih^T + bsum, layout [j][4*hh+q]               (8*512)
#define BSUM_OFF  135168   // (b_ih+b_hh) permuted [q*128+hh]                             (512)

__global__ __launch_bounds__(256) void setup_kernel(
    const float* __restrict__ w_emb, const float* __restrict__ w_ih,
    const float* __restrict__ w_hh, const float* __restrict__ b_ih,
    const float* __restrict__ b_hh, float* __restrict__ ws)
{
  int tid = blockIdx.x * blockDim.x + threadIdx.x;
  if (tid < 65536) {
    int k = tid >> 9, col = tid & 511;
    int hh = col >> 2, q = col & 3;
    ws[WPT_OFF + tid]  = w_hh[(q*HD + hh)*HD + k];
    ws[WIPT_OFF + tid] = w_ih[(q*HD + hh)*HD + k];
  }
  if (tid < 4096) {
    int j = tid >> 9, rem = tid & 511;
    int q = rem >> 7, hh2 = rem & 127;
    const float* wr = w_ih + (q*HD + hh2)*HD;
    const float* er = w_emb + j*HD;
    float s = 0.f;
    for (int k = 0; k < HD; ++k) s = fmaf(er[k], wr[k], s);
    ws[PP_OFF + (size_t)j*512 + 4*hh2 + q] = s + b_ih[q*HD + hh2] + b_hh[q*HD + hh2];
  }
  if (tid < 512) {
    int q = tid >> 7, hh2 = tid & 127;
    ws[BSUM_OFF + tid] = b_ih[q*HD + hh2] + b_hh[q*HD + hh2];
  }
}

__device__ __forceinline__ float fsig(float x) {
  return __fdividef(1.f, 1.f + __expf(-x));
}
__device__ __forceinline__ float ftanh(float x) {
  float ax = fabsf(x);
  float e  = __expf(-2.f * ax);
  float r  = __fdividef(1.f - e, 1.f + e);
  return copysignf(r, x);
}

// direct global->LDS DMA, 16B per lane; LDS dest = wave-uniform base + lane*16
__device__ __forceinline__ void gload16(const float* g, float* l) {
  __builtin_amdgcn_global_load_lds(
      (const __attribute__((address_space(1))) void*)(g),
      (__attribute__((address_space(3))) void*)(l), 16, 0, 0);
}

// 32 explicit-component FMAs for one k
#define ROWQ(qi, wq, HA, HB) \
  acc[qi][0] = fmaf((HA).x, wq, acc[qi][0]); acc[qi][1] = fmaf((HA).y, wq, acc[qi][1]); \
  acc[qi][2] = fmaf((HA).z, wq, acc[qi][2]); acc[qi][3] = fmaf((HA).w, wq, acc[qi][3]); \
  acc[qi][4] = fmaf((HB).x, wq, acc[qi][4]); acc[qi][5] = fmaf((HB).y, wq, acc[qi][5]); \
  acc[qi][6] = fmaf((HB).z, wq, acc[qi][6]); acc[qi][7] = fmaf((HB).w, wq, acc[qi][7]);

#define KFMA(W, HA, HB) \
  ROWQ(0, (W).x, HA, HB) ROWQ(1, (W).y, HA, HB) ROWQ(2, (W).z, HA, HB) ROWQ(3, (W).w, HA, HB)

// consume one 8-k chunk from LDS buffer WB (w) + hT rows HR (broadcast)
#define CONSUME(WB, HR) do { \
    _Pragma("unroll") \
    for (int kk = 0; kk < 8; ++kk) { \
      float4 w  = *(const float4*)((WB) + kk*512 + (hh << 2)); \
      float4 ha = *(const float4*)((HR) + kk*HT_PAD); \
      float4 hb = *(const float4*)((HR) + kk*HT_PAD + 4); \
      KFMA(w, ha, hb); \
    } } while (0)

// stage 4096 floats (one 8-k chunk, or pp) from GSRC into LBUF via DMA (2 issues/thread)
#define STAGE16K(GSRC, LBUF) do { \
    gload16((GSRC) + t4,        (LBUF) + wb4); \
    gload16((GSRC) + 2048 + t4, (LBUF) + 2048 + wb4); \
  } while (0)

#define BAR_LGKM() asm volatile("s_waitcnt lgkmcnt(0)\n\ts_barrier" ::: "memory")
#define BAR_FULL() asm volatile("s_waitcnt vmcnt(0) lgkmcnt(0)\n\ts_barrier" ::: "memory")

__global__ __launch_bounds__(512, 4) void ctrl_kernel(
    const int* __restrict__ class_ids,
    const float* __restrict__ gumbel_u,
    const float* __restrict__ g_emb,
    const float* __restrict__ w_soft,
    const float* __restrict__ ws,
    float* __restrict__ out,
    int Btot)
{
  __shared__ __align__(16) float hT[HD * HT_PAD];           // 18432 B (single buffer)
  __shared__ __align__(16) float wsoft_l[NBR * HD];         // 4096 B
  __shared__ __align__(16) float part_l[TILE_B * PART_PAD]; // 16896 B
  __shared__ __align__(16) float wstage[2 * 4096];          // 32768 B: w chunk double-buffer / pp
  __shared__ int br_l[TILE_B];                              // 128 B   (total ~70.6 KB -> 2 blocks/CU)

  const int tid = threadIdx.x;
  const int b0  = blockIdx.x * TILE_B;
  const size_t BL = (size_t)Btot * LSTEPS;

  const float* __restrict__ wpT  = ws + WPT_OFF;
  const float* __restrict__ wipT = ws + WIPT_OFF;
  const float* __restrict__ ppg  = ws + PP_OFF;

  for (int i = tid; i < NBR*HD; i += 512) wsoft_l[i] = w_soft[i];

  const int hh = tid & 127;   // hidden index
  const int bg = tid >> 7;    // batch group 0..3 (8 batches each)
  const int slb = tid >> 4;   // sampling: batch owned by this 16-lane group
  const int sr  = tid & 15;   // sampling: lane within group
  const int t4  = tid << 2;                                            // per-lane float offset for DMA src
  const int wb4 = __builtin_amdgcn_readfirstlane((tid & 448) << 2);    // wave-uniform LDS float base

  // ---- stage x0^T = g_emb[class_ids]^T into hT ----
  {
    int sb = tid >> 4;
    int kc = tid & 15;
    int cid = class_ids[b0 + sb];
    const float* src = g_emb + (size_t)cid * HD + kc*8;
    float4 v0 = *(const float4*)(src);
    float4 v1 = *(const float4*)(src + 4);
    int kb = kc*8;
    hT[(kb+0)*HT_PAD + sb] = v0.x;
    hT[(kb+1)*HT_PAD + sb] = v0.y;
    hT[(kb+2)*HT_PAD + sb] = v0.z;
    hT[(kb+3)*HT_PAD + sb] = v0.w;
    hT[(kb+4)*HT_PAD + sb] = v1.x;
    hT[(kb+5)*HT_PAD + sb] = v1.y;
    hT[(kb+6)*HT_PAD + sb] = v1.z;
    hT[(kb+7)*HT_PAD + sb] = v1.w;
  }
  __syncthreads();

  // ---- q0h = 0.5*(x0 @ w_ih^T + bsum), parked in 32 AGPRs (R2-proven, no spill) ----
  float qpark[32];
  {
    float acc[4][8];
    #pragma unroll
    for (int q = 0; q < 4; ++q)
      #pragma unroll
      for (int j = 0; j < 8; ++j) acc[q][j] = 0.f;

    const float* wr = wipT + 4*hh;
    const float* hr = hT + bg*8;
    #pragma unroll 2
    for (int k = 0; k < HD; ++k) {
      float4 w  = *(const float4*)(wr);
      float4 ha = *(const float4*)(hr);
      float4 hb = *(const float4*)(hr + 4);
      KFMA(w, ha, hb);
      wr += 512; hr += HT_PAD;
    }
    #pragma unroll
    for (int q = 0; q < 4; ++q) {
      float bs = ws[BSUM_OFF + q*HD + hh];
      #pragma unroll
      for (int j = 0; j < 8; ++j) {
        float v = 0.5f * (acc[q][j] + bs);
        asm("v_accvgpr_write_b32 %0, %1" : "=a"(qpark[q*8+j]) : "v"(v));
      }
    }
  }
  __syncthreads();

  float c[8];
  #pragma unroll
  for (int j = 0; j < 8; ++j) c[j] = 0.f;

  for (int t = 0; t < LSTEPS; ++t) {
    // ---- gumbel load + transform, finalizer lanes only (overlaps GEMM) ----
    float gmb[8];
    if (sr == 0) {
      const float* up = gumbel_u + ((size_t)t * Btot + (b0 + slb)) * NBR;
      float4 ua = *(const float4*)up;
      float4 ub = *(const float4*)(up + 4);
      float uv[8] = {ua.x,ua.y,ua.z,ua.w,ub.x,ub.y,ub.z,ub.w};
      #pragma unroll
      for (int nb = 0; nb < 8; ++nb) {
        float uc = fminf(fmaxf(uv[nb], 1e-8f), 0.99999999f);
        gmb[nb] = -__logf(-__logf(uc));
      }
    }

    // ---- acc starts at parked q0h; GEMM adds h @ w_hh^T, w served from LDS chunks ----
    float acc[4][8];
    #pragma unroll
    for (int q = 0; q < 4; ++q)
      #pragma unroll
      for (int j = 0; j < 8; ++j)
        asm("v_accvgpr_read_b32 %0, %1" : "=v"(acc[q][j]) : "a"(qpark[q*8+j]));

    if (t > 0) {
      // chunk 0 was DMA-staged into wstage[0] during the previous step's partials phase
      // (completion guaranteed by barrier E = BAR_FULL).
      __builtin_amdgcn_s_setprio(1);
      const float* hrb = hT + bg*8;
      #pragma unroll 1
      for (int cc = 0; cc < 8; ++cc) {
        // even chunk c=2cc: consume buf0, stage chunk 2cc+1 -> buf1
        STAGE16K(wpT + (2*cc+1)*4096, wstage + 4096);
        CONSUME(wstage, hrb + (2*cc*8)*HT_PAD);
        BAR_FULL();
        // odd chunk c=2cc+1: consume buf1, stage chunk 2cc+2 -> buf0 (or pp at the end)
        if (cc < 7) { STAGE16K(wpT + (2*cc+2)*4096, wstage); }
        else        { STAGE16K(ppg, wstage); }               // pp -> buf0 for combine
        CONSUME(wstage + 4096, hrb + ((2*cc+1)*8)*HT_PAD);
        BAR_FULL();
      }
      __builtin_amdgcn_s_setprio(0);
      // final BAR_FULL doubles as: all hT reads done (safe to overwrite) + pp staged in buf0
    }

    // ---- combine x-part (pp from LDS buf0), LSTM pointwise ----
    float h2v[8];
    #pragma unroll
    for (int j = 0; j < 8; ++j) {
      float gi, gf, gg, go;
      if (t == 0) {
        gi = 2.f*acc[0][j]; gf = 2.f*acc[1][j];
        gg = 2.f*acc[2][j]; go = 2.f*acc[3][j];
      } else {
        int br = br_l[bg*8 + j];
        float4 pv = *(const float4*)(&wstage[br*512 + 4*hh]);
        gi = fmaf(0.5f, pv.x, acc[0][j]);
        gf = fmaf(0.5f, pv.y, acc[1][j]);
        gg = fmaf(0.5f, pv.z, acc[2][j]);
        go = fmaf(0.5f, pv.w, acc[3][j]);
      }
      float iv = fsig(gi);
      float fv = fsig(gf);
      float gv = ftanh(gg);
      float ov = fsig(go);
      float c2 = fmaf(fv, c[j], iv*gv);
      c[j] = c2;
      h2v[j] = ov * ftanh(c2);
    }

    // write h_{t+1} (single buffer: all reads completed at last chunk barrier / t=0 sync)
    {
      float* dst = &hT[hh*HT_PAD + bg*8];
      *(float4*)(dst)   = make_float4(h2v[0],h2v[1],h2v[2],h2v[3]);
      *(float4*)(dst+4) = make_float4(h2v[4],h2v[5],h2v[6],h2v[7]);
    }
    BAR_LGKM();   // (B) new h visible; also: all combine reads of buf0 (pp) are drained

    // ---- partials phase; also DMA-prefetch next step's w chunk 0 into buf0 ----
    STAGE16K(wpT, wstage);   // completion enforced at barrier E (BAR_FULL)
    {
      int lb = tid & 31, ch = tid >> 5;
      const float* hp = hT + (ch*8)*HT_PAD + lb;
      float hv[8];
      #pragma unroll
      for (int i = 0; i < 8; ++i) hv[i] = hp[i*HT_PAD];
      #pragma unroll
      for (int nb = 0; nb < 8; ++nb) {
        const float4* wr2 = (const float4*)&wsoft_l[nb*HD + ch*8];
        float4 wa = wr2[0], wb = wr2[1];
        float p = 0.f;
        p = fmaf(hv[0], wa.x, p); p = fmaf(hv[1], wa.y, p);
        p = fmaf(hv[2], wa.z, p); p = fmaf(hv[3], wa.w, p);
        p = fmaf(hv[4], wb.x, p); p = fmaf(hv[5], wb.y, p);
        p = fmaf(hv[6], wb.z, p); p = fmaf(hv[7], wb.w, p);
        part_l[lb*PART_PAD + nb*16 + ch] = p;
      }
    }
    BAR_LGKM();   // (C) partials visible

    // ---- sampling: 16-lane group per batch, butterfly reduce, lane 0 finalizes ----
    {
      float s[8];
      #pragma unroll
      for (int nb = 0; nb < 8; ++nb)
        s[nb] = part_l[slb*PART_PAD + nb*16 + sr];
      #pragma unroll
      for (int mk = 1; mk < 16; mk <<= 1) {
        #pragma unroll
        for (int nb = 0; nb < 8; ++nb)
          s[nb] += __shfl_xor(s[nb], mk, 64);
      }
      if (sr == 0) {
        float lg[8];
        #pragma unroll
        for (int nb = 0; nb < 8; ++nb)
          lg[nb] = 2.5f * ftanh(s[nb] * 0.2f);
        int br = 0; float best = lg[0] + gmb[0];
        #pragma unroll
        for (int nb = 1; nb < 8; ++nb) {
          float y = lg[nb] + gmb[nb];
          if (y > best) { best = y; br = nb; }   // strict > == first-occurrence argmax
        }
        br_l[slb] = br;
        float m = lg[0];
        #pragma unroll
        for (int nb = 1; nb < 8; ++nb) m = fmaxf(m, lg[nb]);
        float se = 0.f;
        #pragma unroll
        for (int nb = 0; nb < 8; ++nb) se += __expf(lg[nb] - m);
        float lse = __logf(se);
        float lp = (lg[br] - m) - lse;
        float ent = 0.f;
        #pragma unroll
        for (int nb = 0; nb < 8; ++nb) {
          float lpi = (lg[nb] - m) - lse;
          ent -= __expf(lpi) * lpi;
        }
        size_t row = (size_t)(b0 + slb) * LSTEPS + t;
        out[row]        = (float)br;
        out[BL + row]   = lp;
        out[2*BL + row] = ent;
        out[3*BL + row] = __expf(lp);
      }
    }
    BAR_FULL();   // (E) br_l visible + next-step chunk-0 DMA complete in all waves
  }
}

extern "C" void kernel_launch(void* const* d_in, const int* in_sizes, int n_in,
                              void* d_out, int out_size, void* d_ws, size_t ws_size,
                              hipStream_t stream) {
  const int*   class_ids = (const int*)d_in[0];
  const float* gumbel_u  = (const float*)d_in[1];
  const float* g_emb     = (const float*)d_in[2];
  const float* w_emb     = (const float*)d_in[3];
  const float* w_soft    = (const float*)d_in[4];
  const float* w_ih      = (const float*)d_in[5];
  const float* w_hh      = (const float*)d_in[6];
  const float* b_ih      = (const float*)d_in[7];
  const float* b_hh      = (const float*)d_in[8];
  float* out = (float*)d_out;
  float* ws  = (float*)d_ws;
  int B = in_sizes[0];

  hipLaunchKernelGGL(setup_kernel, dim3(256), dim3(256), 0, stream,
                     w_emb, w_ih, w_hh, b_ih, b_hh, ws);
  hipLaunchKernelGGL(ctrl_kernel, dim3(B / TILE_B), dim3(512), 0, stream,
                     class_ids, gumbel_u, g_emb, w_soft, ws, out, B);
}

// Round 7
// 2052.539 us; speedup vs baseline: 1.8294x; 1.8294x over previous
//
#include <hip/hip_runtime.h>
#include <math.h>

#define HD 128
#define NBR 8
#define LSTEPS 64
#define TILE_B 32
#define HT_PAD 36     // 144B rows: float4-aligned; GEMM h-reads are wave-uniform broadcasts
#define PART_PAD 68   // 68%32=4: mild 2-4 way on a tiny phase

// workspace layout (floats)
#define WPT_OFF   0        // w_hh permuted-transposed: [k][4*hh+q] = w_hh[q*128+hh][k]   (128*512)
#define WIPT_OFF  65536    // w_ih same layout                                            (128*512)
#define PP_OFF    131072   // P'' = w_emb@w_ih^T + bsum, layout [j][4*hh+q]               (8*512)
#define BSUM_OFF  135168   // (b_ih+b_hh) permuted [q*128+hh]                             (512)

__global__ __launch_bounds__(256) void setup_kernel(
    const float* __restrict__ w_emb, const float* __restrict__ w_ih,
    const float* __restrict__ w_hh, const float* __restrict__ b_ih,
    const float* __restrict__ b_hh, float* __restrict__ ws)
{
  int tid = blockIdx.x * blockDim.x + threadIdx.x;
  if (tid < 65536) {
    int k = tid >> 9, col = tid & 511;
    int hh = col >> 2, q = col & 3;
    ws[WPT_OFF + tid]  = w_hh[(q*HD + hh)*HD + k];
    ws[WIPT_OFF + tid] = w_ih[(q*HD + hh)*HD + k];
  }
  if (tid < 4096) {
    int j = tid >> 9, rem = tid & 511;
    int q = rem >> 7, hh2 = rem & 127;
    const float* wr = w_ih + (q*HD + hh2)*HD;
    const float* er = w_emb + j*HD;
    float s = 0.f;
    for (int k = 0; k < HD; ++k) s = fmaf(er[k], wr[k], s);
    ws[PP_OFF + (size_t)j*512 + 4*hh2 + q] = s + b_ih[q*HD + hh2] + b_hh[q*HD + hh2];
  }
  if (tid < 512) {
    int q = tid >> 7, hh2 = tid & 127;
    ws[BSUM_OFF + tid] = b_ih[q*HD + hh2] + b_hh[q*HD + hh2];
  }
}

__device__ __forceinline__ float fsig(float x) {
  return __fdividef(1.f, 1.f + __expf(-x));
}
__device__ __forceinline__ float ftanh(float x) {
  float ax = fabsf(x);
  float e  = __expf(-2.f * ax);
  float r  = __fdividef(1.f - e, 1.f + e);
  return copysignf(r, x);
}

// 16 batches per thread: 64 explicit-component FMAs per k
#define ROWQ16(qi, wq) \
  acc[qi][0]  = fmaf(ha.x, wq, acc[qi][0]);  acc[qi][1]  = fmaf(ha.y, wq, acc[qi][1]);  \
  acc[qi][2]  = fmaf(ha.z, wq, acc[qi][2]);  acc[qi][3]  = fmaf(ha.w, wq, acc[qi][3]);  \
  acc[qi][4]  = fmaf(hb.x, wq, acc[qi][4]);  acc[qi][5]  = fmaf(hb.y, wq, acc[qi][5]);  \
  acc[qi][6]  = fmaf(hb.z, wq, acc[qi][6]);  acc[qi][7]  = fmaf(hb.w, wq, acc[qi][7]);  \
  acc[qi][8]  = fmaf(hc.x, wq, acc[qi][8]);  acc[qi][9]  = fmaf(hc.y, wq, acc[qi][9]);  \
  acc[qi][10] = fmaf(hc.z, wq, acc[qi][10]); acc[qi][11] = fmaf(hc.w, wq, acc[qi][11]); \
  acc[qi][12] = fmaf(hd.x, wq, acc[qi][12]); acc[qi][13] = fmaf(hd.y, wq, acc[qi][13]); \
  acc[qi][14] = fmaf(hd.z, wq, acc[qi][14]); acc[qi][15] = fmaf(hd.w, wq, acc[qi][15]);

#define KFMA16(W) \
  ROWQ16(0, (W).x) ROWQ16(1, (W).y) ROWQ16(2, (W).z) ROWQ16(3, (W).w)

#define LOADH(HP) \
  float4 ha = *(const float4*)(HP); \
  float4 hb = *(const float4*)((HP) + 4); \
  float4 hc = *(const float4*)((HP) + 8); \
  float4 hd = *(const float4*)((HP) + 12);

// lgkm-only barrier: no vmcnt(0) drain (out-stores stay in flight)
#define BAR_LGKM() asm volatile("s_waitcnt lgkmcnt(0)\n\ts_barrier" ::: "memory")

__global__ __launch_bounds__(256, 2) void ctrl_kernel(
    const int* __restrict__ class_ids,
    const float* __restrict__ gumbel_u,
    const float* __restrict__ g_emb,
    const float* __restrict__ w_soft,
    const float* __restrict__ ws,
    float* __restrict__ out,
    int Btot)
{
  __shared__ __align__(16) float hT0[HD * HT_PAD];          // 18432 B
  __shared__ __align__(16) float hT1[HD * HT_PAD];          // 18432 B
  __shared__ __align__(16) float wsoft_l[NBR * HD];         // 4096 B
  __shared__ __align__(16) float part_l[TILE_B * PART_PAD]; // 8704 B
  __shared__ __align__(16) float pp_l[NBR * 512];           // 16384 B
  __shared__ int br_l[TILE_B];                              // 128 B  (~64.6 KB -> 2 blocks/CU)

  const int tid = threadIdx.x;
  const int b0  = blockIdx.x * TILE_B;
  const size_t BL = (size_t)Btot * LSTEPS;

  const float* __restrict__ wpT  = ws + WPT_OFF;
  const float* __restrict__ wipT = ws + WIPT_OFF;

  for (int i = tid; i < NBR*HD; i += 256) wsoft_l[i] = w_soft[i];
  for (int i = tid; i < NBR*512; i += 256) pp_l[i] = ws[PP_OFF + i];

  const int hh = tid & 127;   // hidden/gate index (w cols 4*hh..4*hh+3)
  const int bg = tid >> 7;    // batch half: 0 -> batches 0..15, 1 -> 16..31
  const int slb = tid >> 3;   // sampling: batch owned by this 8-lane group (0..31)
  const int sr  = tid & 7;    // sampling: lane within group

  // ---- stage x0^T = g_emb[class_ids]^T into hT0 ----
  {
    int sb = tid >> 3;        // 0..31 batch
    int kc = tid & 7;         // k-chunk of 16
    int cid = class_ids[b0 + sb];
    const float* src = g_emb + (size_t)cid * HD + kc*16;
    #pragma unroll
    for (int ii = 0; ii < 4; ++ii) {
      float4 v = *(const float4*)(src + 4*ii);
      int kb = kc*16 + 4*ii;
      hT0[(kb+0)*HT_PAD + sb] = v.x;
      hT0[(kb+1)*HT_PAD + sb] = v.y;
      hT0[(kb+2)*HT_PAD + sb] = v.z;
      hT0[(kb+3)*HT_PAD + sb] = v.w;
    }
  }
  __syncthreads();

  // ---- q0 = 0.5*(x0 @ w_ih^T + bsum) for 16 batches, plain registers ----
  float q0[4][16];
  {
    float acc[4][16];
    #pragma unroll
    for (int q = 0; q < 4; ++q)
      #pragma unroll
      for (int j = 0; j < 16; ++j) acc[q][j] = 0.f;

    const float* wr = wipT + 4*hh;
    const float* hr = hT0 + bg*16;
    #pragma unroll 2
    for (int k = 0; k < HD; ++k) {
      float4 w = *(const float4*)(wr);
      LOADH(hr);
      KFMA16(w);
      wr += 512; hr += HT_PAD;
    }
    #pragma unroll
    for (int q = 0; q < 4; ++q) {
      float bs = ws[BSUM_OFF + q*HD + hh];
      #pragma unroll
      for (int j = 0; j < 16; ++j)
        q0[q][j] = 0.5f * (acc[q][j] + bs);
    }
  }
  __syncthreads();

  float c[16];
  #pragma unroll
  for (int j = 0; j < 16; ++j) c[j] = 0.f;

  float* hcur = hT0;
  float* hnxt = hT1;

  for (int t = 0; t < LSTEPS; ++t) {
    // ---- gumbel load + transform, finalizer lanes only (overlaps GEMM) ----
    float gmb[8];
    if (sr == 0) {
      const float* up = gumbel_u + ((size_t)t * Btot + (b0 + slb)) * NBR;
      float4 ua = *(const float4*)up;
      float4 ub = *(const float4*)(up + 4);
      float uv[8] = {ua.x,ua.y,ua.z,ua.w,ub.x,ub.y,ub.z,ub.w};
      #pragma unroll
      for (int nb = 0; nb < 8; ++nb) {
        float uc = fminf(fmaxf(uv[nb], 1e-8f), 0.99999999f);
        gmb[nb] = -__logf(-__logf(uc));
      }
    }

    // ---- acc starts at q0 (x0-part + bias pre-folded); GEMM adds h @ w_hh^T ----
    float acc[4][16];
    #pragma unroll
    for (int q = 0; q < 4; ++q)
      #pragma unroll
      for (int j = 0; j < 16; ++j) acc[q][j] = q0[q][j];

    if (t > 0) {
      __builtin_amdgcn_s_setprio(1);
      const float* wr = wpT + 4*hh;
      const float* hr = hcur + bg*16;
      #pragma unroll 2
      for (int k = 0; k < HD; ++k) {
        float4 w = *(const float4*)(wr);
        LOADH(hr);
        KFMA16(w);
        wr += 512; hr += HT_PAD;
      }
      __builtin_amdgcn_s_setprio(0);
    }

    // ---- combine x-part, LSTM pointwise ----
    float h2v[16];
    #pragma unroll
    for (int j = 0; j < 16; ++j) {
      float gi, gf, gg, go;
      if (t == 0) {
        gi = 2.f*acc[0][j]; gf = 2.f*acc[1][j];
        gg = 2.f*acc[2][j]; go = 2.f*acc[3][j];
      } else {
        int br = br_l[bg*16 + j];
        float4 pv = *(const float4*)(&pp_l[br*512 + 4*hh]);
        gi = fmaf(0.5f, pv.x, acc[0][j]);
        gf = fmaf(0.5f, pv.y, acc[1][j]);
        gg = fmaf(0.5f, pv.z, acc[2][j]);
        go = fmaf(0.5f, pv.w, acc[3][j]);
      }
      float iv = fsig(gi);
      float fv = fsig(gf);
      float gv = ftanh(gg);
      float ov = fsig(go);
      float c2 = fmaf(fv, c[j], iv*gv);
      c[j] = c2;
      h2v[j] = ov * ftanh(c2);
    }

    // write h_{t+1} into the other buffer (no pre-write barrier needed)
    {
      float* dst = &hnxt[hh*HT_PAD + bg*16];
      *(float4*)(dst)    = make_float4(h2v[0], h2v[1], h2v[2], h2v[3]);
      *(float4*)(dst+4)  = make_float4(h2v[4], h2v[5], h2v[6], h2v[7]);
      *(float4*)(dst+8)  = make_float4(h2v[8], h2v[9], h2v[10],h2v[11]);
      *(float4*)(dst+12) = make_float4(h2v[12],h2v[13],h2v[14],h2v[15]);
    }
    BAR_LGKM();   // (B) new h visible (LDS only)

    // ---- logit partials: thread (lb = tid&31, ch = tid>>5 in 0..7), 16-k chunk each ----
    {
      int lb = tid & 31, ch = tid >> 5;
      const float* hp = hnxt + (ch*16)*HT_PAD + lb;
      float hv[16];
      #pragma unroll
      for (int i = 0; i < 16; ++i) hv[i] = hp[i*HT_PAD];
      #pragma unroll
      for (int nb = 0; nb < 8; ++nb) {
        const float4* wr2 = (const float4*)&wsoft_l[nb*HD + ch*16];
        float4 wa = wr2[0], wb = wr2[1], wc = wr2[2], wd = wr2[3];
        float p = 0.f;
        p = fmaf(hv[0],  wa.x, p); p = fmaf(hv[1],  wa.y, p);
        p = fmaf(hv[2],  wa.z, p); p = fmaf(hv[3],  wa.w, p);
        p = fmaf(hv[4],  wb.x, p); p = fmaf(hv[5],  wb.y, p);
        p = fmaf(hv[6],  wb.z, p); p = fmaf(hv[7],  wb.w, p);
        p = fmaf(hv[8],  wc.x, p); p = fmaf(hv[9],  wc.y, p);
        p = fmaf(hv[10], wc.z, p); p = fmaf(hv[11], wc.w, p);
        p = fmaf(hv[12], wd.x, p); p = fmaf(hv[13], wd.y, p);
        p = fmaf(hv[14], wd.z, p); p = fmaf(hv[15], wd.w, p);
        part_l[lb*PART_PAD + nb*8 + ch] = p;
      }
    }
    BAR_LGKM();   // (C) partials visible

    // ---- sampling: 8-lane group per batch, butterfly reduce, lane 0 finalizes ----
    {
      float s[8];
      #pragma unroll
      for (int nb = 0; nb < 8; ++nb)
        s[nb] = part_l[slb*PART_PAD + nb*8 + sr];
      #pragma unroll
      for (int mk = 1; mk < 8; mk <<= 1) {
        #pragma unroll
        for (int nb = 0; nb < 8; ++nb)
          s[nb] += __shfl_xor(s[nb], mk, 64);   // masks 1,2,4 stay within the 8-group
      }
      if (sr == 0) {
        float lg[8];
        #pragma unroll
        for (int nb = 0; nb < 8; ++nb)
          lg[nb] = 2.5f * ftanh(s[nb] * 0.2f);
        int br = 0; float best = lg[0] + gmb[0];
        #pragma unroll
        for (int nb = 1; nb < 8; ++nb) {
          float y = lg[nb] + gmb[nb];
          if (y > best) { best = y; br = nb; }   // strict > == first-occurrence argmax
        }
        br_l[slb] = br;
        float m = lg[0];
        #pragma unroll
        for (int nb = 1; nb < 8; ++nb) m = fmaxf(m, lg[nb]);
        float se = 0.f;
        #pragma unroll
        for (int nb = 0; nb < 8; ++nb) se += __expf(lg[nb] - m);
        float lse = __logf(se);
        float lp = (lg[br] - m) - lse;
        float ent = 0.f;
        #pragma unroll
        for (int nb = 0; nb < 8; ++nb) {
          float lpi = (lg[nb] - m) - lse;
          ent -= __expf(lpi) * lpi;
        }
        size_t row = (size_t)(b0 + slb) * LSTEPS + t;
        out[row]        = (float)br;
        out[BL + row]   = lp;
        out[2*BL + row] = ent;
        out[3*BL + row] = __expf(lp);
      }
    }
    BAR_LGKM();   // (E) br_l visible for next step's combine

    float* tmp = hcur; hcur = hnxt; hnxt = tmp;
  }
}

extern "C" void kernel_launch(void* const* d_in, const int* in_sizes, int n_in,
                              void* d_out, int out_size, void* d_ws, size_t ws_size,
                              hipStream_t stream) {
  const int*   class_ids = (const int*)d_in[0];
  const float* gumbel_u  = (const float*)d_in[1];
  const float* g_emb     = (const float*)d_in[2];
  const float* w_emb     = (const float*)d_in[3];
  const float* w_soft    = (const float*)d_in[4];
  const float* w_ih      = (const float*)d_in[5];
  const float* w_hh      = (const float*)d_in[6];
  const float* b_ih      = (const float*)d_in[7];
  const float* b_hh      = (const float*)d_in[8];
  float* out = (float*)d_out;
  float* ws  = (float*)d_ws;
  int B = in_sizes[0];

  hipLaunchKernelGGL(setup_kernel, dim3(256), dim3(256), 0, stream,
                     w_emb, w_ih, w_hh, b_ih, b_hh, ws);
  hipLaunchKernelGGL(ctrl_kernel, dim3(B / TILE_B), dim3(256), 0, stream,
                     class_ids, gumbel_u, g_emb, w_soft, ws, out, B);
}

// Round 8
// 1960.155 us; speedup vs baseline: 1.9156x; 1.0471x over previous
//
#include <hip/hip_runtime.h>
#include <math.h>

#define HD 128
#define NBR 8
#define LSTEPS 64
#define TILE_B 32
#define HT_PAD 36     // 144B rows: float4-aligned; GEMM h-reads are wave-uniform broadcasts
#define PART_PAD 68   // 68%32=4: mild 2-4 way on a tiny phase

// workspace layout (floats)
#define WPT_OFF   0        // w_hh permuted-transposed: [k][4*hh+q] = w_hh[q*128+hh][k]   (128*512)
#define WIPT_OFF  65536    // w_ih same layout                                            (128*512)
#define PP_OFF    131072   // P'' = w_emb@w_ih^T + bsum, layout [j][4*hh+q]               (8*512)
#define BSUM_OFF  135168   // (b_ih+b_hh) permuted [q*128+hh]                             (512)

__global__ __launch_bounds__(256) void setup_kernel(
    const float* __restrict__ w_emb, const float* __restrict__ w_ih,
    const float* __restrict__ w_hh, const float* __restrict__ b_ih,
    const float* __restrict__ b_hh, float* __restrict__ ws)
{
  int tid = blockIdx.x * blockDim.x + threadIdx.x;
  if (tid < 65536) {
    int k = tid >> 9, col = tid & 511;
    int hh = col >> 2, q = col & 3;
    ws[WPT_OFF + tid]  = w_hh[(q*HD + hh)*HD + k];
    ws[WIPT_OFF + tid] = w_ih[(q*HD + hh)*HD + k];
  }
  if (tid < 4096) {
    int j = tid >> 9, rem = tid & 511;
    int q = rem >> 7, hh2 = rem & 127;
    const float* wr = w_ih + (q*HD + hh2)*HD;
    const float* er = w_emb + j*HD;
    float s = 0.f;
    for (int k = 0; k < HD; ++k) s = fmaf(er[k], wr[k], s);
    ws[PP_OFF + (size_t)j*512 + 4*hh2 + q] = s + b_ih[q*HD + hh2] + b_hh[q*HD + hh2];
  }
  if (tid < 512) {
    int q = tid >> 7, hh2 = tid & 127;
    ws[BSUM_OFF + tid] = b_ih[q*HD + hh2] + b_hh[q*HD + hh2];
  }
}

__device__ __forceinline__ float fsig(float x) {
  return __fdividef(1.f, 1.f + __expf(-x));
}
__device__ __forceinline__ float ftanh(float x) {
  float ax = fabsf(x);
  float e  = __expf(-2.f * ax);
  float r  = __fdividef(1.f - e, 1.f + e);
  return copysignf(r, x);
}

// 16 batches per thread: 64 explicit-component FMAs per k (named h vectors)
#define ROWQ16(qi, wq, H0, H1, H2, H3) \
  acc[qi][0]  = fmaf((H0).x, wq, acc[qi][0]);  acc[qi][1]  = fmaf((H0).y, wq, acc[qi][1]);  \
  acc[qi][2]  = fmaf((H0).z, wq, acc[qi][2]);  acc[qi][3]  = fmaf((H0).w, wq, acc[qi][3]);  \
  acc[qi][4]  = fmaf((H1).x, wq, acc[qi][4]);  acc[qi][5]  = fmaf((H1).y, wq, acc[qi][5]);  \
  acc[qi][6]  = fmaf((H1).z, wq, acc[qi][6]);  acc[qi][7]  = fmaf((H1).w, wq, acc[qi][7]);  \
  acc[qi][8]  = fmaf((H2).x, wq, acc[qi][8]);  acc[qi][9]  = fmaf((H2).y, wq, acc[qi][9]);  \
  acc[qi][10] = fmaf((H2).z, wq, acc[qi][10]); acc[qi][11] = fmaf((H2).w, wq, acc[qi][11]); \
  acc[qi][12] = fmaf((H3).x, wq, acc[qi][12]); acc[qi][13] = fmaf((H3).y, wq, acc[qi][13]); \
  acc[qi][14] = fmaf((H3).z, wq, acc[qi][14]); acc[qi][15] = fmaf((H3).w, wq, acc[qi][15]);

#define KFMA16(W, H0, H1, H2, H3) \
  ROWQ16(0, (W).x, H0, H1, H2, H3) ROWQ16(1, (W).y, H0, H1, H2, H3) \
  ROWQ16(2, (W).z, H0, H1, H2, H3) ROWQ16(3, (W).w, H0, H1, H2, H3)

// lgkm-only barrier: no vmcnt(0) drain (out-stores stay in flight)
#define BAR_LGKM() asm volatile("s_waitcnt lgkmcnt(0)\n\ts_barrier" ::: "memory")

__global__ __launch_bounds__(256, 2) void ctrl_kernel(
    const int* __restrict__ class_ids,
    const float* __restrict__ gumbel_u,
    const float* __restrict__ g_emb,
    const float* __restrict__ w_soft,
    const float* __restrict__ ws,
    float* __restrict__ out,
    int Btot)
{
  __shared__ __align__(16) float hT0[HD * HT_PAD];          // 18432 B
  __shared__ __align__(16) float hT1[HD * HT_PAD];          // 18432 B
  __shared__ __align__(16) float wsoft_l[NBR * HD];         // 4096 B
  __shared__ __align__(16) float part_l[TILE_B * PART_PAD]; // 8704 B
  __shared__ __align__(16) float pp_l[NBR * 512];           // 16384 B
  __shared__ int br_l[TILE_B];                              // 128 B  (~64.6 KB -> 2 blocks/CU)

  const int tid = threadIdx.x;
  const int b0  = blockIdx.x * TILE_B;
  const size_t BL = (size_t)Btot * LSTEPS;

  const float* __restrict__ wpT  = ws + WPT_OFF;
  const float* __restrict__ wipT = ws + WIPT_OFF;

  for (int i = tid; i < NBR*HD; i += 256) wsoft_l[i] = w_soft[i];
  for (int i = tid; i < NBR*512; i += 256) pp_l[i] = ws[PP_OFF + i];

  const int hh = tid & 127;   // hidden/gate index (w cols 4*hh..4*hh+3)
  const int bg = tid >> 7;    // batch half: 0 -> batches 0..15, 1 -> 16..31
  const int slb = tid >> 3;   // sampling: batch owned by this 8-lane group (0..31)
  const int sr  = tid & 7;    // sampling: lane within group

  // ---- stage x0^T = g_emb[class_ids]^T into hT0 ----
  {
    int sb = tid >> 3;        // 0..31 batch
    int kc = tid & 7;         // k-chunk of 16
    int cid = class_ids[b0 + sb];
    const float* src = g_emb + (size_t)cid * HD + kc*16;
    #pragma unroll
    for (int ii = 0; ii < 4; ++ii) {
      float4 v = *(const float4*)(src + 4*ii);
      int kb = kc*16 + 4*ii;
      hT0[(kb+0)*HT_PAD + sb] = v.x;
      hT0[(kb+1)*HT_PAD + sb] = v.y;
      hT0[(kb+2)*HT_PAD + sb] = v.z;
      hT0[(kb+3)*HT_PAD + sb] = v.w;
    }
  }
  __syncthreads();

  // ---- q0 = 0.5*(x0 @ w_ih^T + bsum) for 16 batches, plain registers ----
  float q0[4][16];
  {
    float acc[4][16];
    #pragma unroll
    for (int q = 0; q < 4; ++q)
      #pragma unroll
      for (int j = 0; j < 16; ++j) acc[q][j] = 0.f;

    const float* wr = wipT + 4*hh;
    const float* hr = hT0 + bg*16;
    #pragma unroll 2
    for (int k = 0; k < HD; ++k) {
      float4 w  = *(const float4*)(wr);
      float4 h0 = *(const float4*)(hr);
      float4 h1 = *(const float4*)(hr + 4);
      float4 h2 = *(const float4*)(hr + 8);
      float4 h3 = *(const float4*)(hr + 12);
      KFMA16(w, h0, h1, h2, h3);
      wr += 512; hr += HT_PAD;
    }
    #pragma unroll
    for (int q = 0; q < 4; ++q) {
      float bs = ws[BSUM_OFF + q*HD + hh];
      #pragma unroll
      for (int j = 0; j < 16; ++j)
        q0[q][j] = 0.5f * (acc[q][j] + bs);
    }
  }
  __syncthreads();

  float c[16];
  #pragma unroll
  for (int j = 0; j < 16; ++j) c[j] = 0.f;

  float* hcur = hT0;
  float* hnxt = hT1;

  for (int t = 0; t < LSTEPS; ++t) {
    // ---- gumbel load + transform, finalizer lanes only (overlaps GEMM) ----
    float gmb[8];
    if (sr == 0) {
      const float* up = gumbel_u + ((size_t)t * Btot + (b0 + slb)) * NBR;
      float4 ua = *(const float4*)up;
      float4 ub = *(const float4*)(up + 4);
      float uv[8] = {ua.x,ua.y,ua.z,ua.w,ub.x,ub.y,ub.z,ub.w};
      #pragma unroll
      for (int nb = 0; nb < 8; ++nb) {
        float uc = fminf(fmaxf(uv[nb], 1e-8f), 0.99999999f);
        gmb[nb] = -__logf(-__logf(uc));
      }
    }

    // ---- acc starts at q0 (x0-part + bias pre-folded); GEMM adds h @ w_hh^T ----
    float acc[4][16];
    #pragma unroll
    for (int q = 0; q < 4; ++q)
      #pragma unroll
      for (int j = 0; j < 16; ++j) acc[q][j] = q0[q][j];

    if (t > 0) {
      __builtin_amdgcn_s_setprio(1);
      const float* wr = wpT + 4*hh;
      const float* hr = hcur + bg*16;
      // software pipeline: w 2-k deep (~280 cyc > L2 latency), h 1-k deep (~140 > LDS latency)
      float4 w0 = *(const float4*)(wr);
      float4 w1 = *(const float4*)(wr + 512);
      float4 hA0 = *(const float4*)(hr);
      float4 hA1 = *(const float4*)(hr + 4);
      float4 hA2 = *(const float4*)(hr + 8);
      float4 hA3 = *(const float4*)(hr + 12);
      #pragma unroll 1
      for (int i = 0; i < 63; ++i) {
        // issue h(2i+1) early; it is consumed after KFMA(w0,...) (~140 cyc later)
        float4 hB0 = *(const float4*)(hr + HT_PAD);
        float4 hB1 = *(const float4*)(hr + HT_PAD + 4);
        float4 hB2 = *(const float4*)(hr + HT_PAD + 8);
        float4 hB3 = *(const float4*)(hr + HT_PAD + 12);
        float4 wn0 = *(const float4*)(wr + 2*512);        // w(2i+2): used next iter, 1st half
        float4 wc0 = w0;
        KFMA16(wc0, hA0, hA1, hA2, hA3);                  // k = 2i
        float4 hN0 = *(const float4*)(hr + 2*HT_PAD);     // h(2i+2): used next iter
        float4 hN1 = *(const float4*)(hr + 2*HT_PAD + 4);
        float4 hN2 = *(const float4*)(hr + 2*HT_PAD + 8);
        float4 hN3 = *(const float4*)(hr + 2*HT_PAD + 12);
        float4 wn1 = *(const float4*)(wr + 3*512);        // w(2i+3): used next iter, 2nd half
        float4 wc1 = w1;
        KFMA16(wc1, hB0, hB1, hB2, hB3);                  // k = 2i+1
        w0 = wn0; w1 = wn1;
        hA0 = hN0; hA1 = hN1; hA2 = hN2; hA3 = hN3;
        wr += 1024; hr += 2*HT_PAD;
      }
      // epilogue: k = 126, 127 (no prefetch past the end)
      {
        float4 hB0 = *(const float4*)(hr + HT_PAD);
        float4 hB1 = *(const float4*)(hr + HT_PAD + 4);
        float4 hB2 = *(const float4*)(hr + HT_PAD + 8);
        float4 hB3 = *(const float4*)(hr + HT_PAD + 12);
        KFMA16(w0, hA0, hA1, hA2, hA3);
        KFMA16(w1, hB0, hB1, hB2, hB3);
      }
      __builtin_amdgcn_s_setprio(0);
    }

    // ---- combine x-part, LSTM pointwise ----
    float h2v[16];
    #pragma unroll
    for (int j = 0; j < 16; ++j) {
      float gi, gf, gg, go;
      if (t == 0) {
        gi = 2.f*acc[0][j]; gf = 2.f*acc[1][j];
        gg = 2.f*acc[2][j]; go = 2.f*acc[3][j];
      } else {
        int br = br_l[bg*16 + j];
        float4 pv = *(const float4*)(&pp_l[br*512 + 4*hh]);
        gi = fmaf(0.5f, pv.x, acc[0][j]);
        gf = fmaf(0.5f, pv.y, acc[1][j]);
        gg = fmaf(0.5f, pv.z, acc[2][j]);
        go = fmaf(0.5f, pv.w, acc[3][j]);
      }
      float iv = fsig(gi);
      float fv = fsig(gf);
      float gv = ftanh(gg);
      float ov = fsig(go);
      float c2 = fmaf(fv, c[j], iv*gv);
      c[j] = c2;
      h2v[j] = ov * ftanh(c2);
    }

    // write h_{t+1} into the other buffer (no pre-write barrier needed)
    {
      float* dst = &hnxt[hh*HT_PAD + bg*16];
      *(float4*)(dst)    = make_float4(h2v[0], h2v[1], h2v[2], h2v[3]);
      *(float4*)(dst+4)  = make_float4(h2v[4], h2v[5], h2v[6], h2v[7]);
      *(float4*)(dst+8)  = make_float4(h2v[8], h2v[9], h2v[10],h2v[11]);
      *(float4*)(dst+12) = make_float4(h2v[12],h2v[13],h2v[14],h2v[15]);
    }
    BAR_LGKM();   // (B) new h visible (LDS only)

    // ---- logit partials: thread (lb = tid&31, ch = tid>>5 in 0..7), 16-k chunk each ----
    {
      int lb = tid & 31, ch = tid >> 5;
      const float* hp = hnxt + (ch*16)*HT_PAD + lb;
      float hv[16];
      #pragma unroll
      for (int i = 0; i < 16; ++i) hv[i] = hp[i*HT_PAD];
      #pragma unroll
      for (int nb = 0; nb < 8; ++nb) {
        const float4* wr2 = (const float4*)&wsoft_l[nb*HD + ch*16];
        float4 wa = wr2[0], wb = wr2[1], wc = wr2[2], wd = wr2[3];
        float p = 0.f;
        p = fmaf(hv[0],  wa.x, p); p = fmaf(hv[1],  wa.y, p);
        p = fmaf(hv[2],  wa.z, p); p = fmaf(hv[3],  wa.w, p);
        p = fmaf(hv[4],  wb.x, p); p = fmaf(hv[5],  wb.y, p);
        p = fmaf(hv[6],  wb.z, p); p = fmaf(hv[7],  wb.w, p);
        p = fmaf(hv[8],  wc.x, p); p = fmaf(hv[9],  wc.y, p);
        p = fmaf(hv[10], wc.z, p); p = fmaf(hv[11], wc.w, p);
        p = fmaf(hv[12], wd.x, p); p = fmaf(hv[13], wd.y, p);
        p = fmaf(hv[14], wd.z, p); p = fmaf(hv[15], wd.w, p);
        part_l[lb*PART_PAD + nb*8 + ch] = p;
      }
    }
    BAR_LGKM();   // (C) partials visible

    // ---- sampling: 8-lane group per batch, butterfly reduce, lane 0 finalizes ----
    {
      float s[8];
      #pragma unroll
      for (int nb = 0; nb < 8; ++nb)
        s[nb] = part_l[slb*PART_PAD + nb*8 + sr];
      #pragma unroll
      for (int mk = 1; mk < 8; mk <<= 1) {
        #pragma unroll
        for (int nb = 0; nb < 8; ++nb)
          s[nb] += __shfl_xor(s[nb], mk, 64);   // masks 1,2,4 stay within the 8-group
      }
      if (sr == 0) {
        float lg[8];
        #pragma unroll
        for (int nb = 0; nb < 8; ++nb)
          lg[nb] = 2.5f * ftanh(s[nb] * 0.2f);
        int br = 0; float best = lg[0] + gmb[0];
        #pragma unroll
        for (int nb = 1; nb < 8; ++nb) {
          float y = lg[nb] + gmb[nb];
          if (y > best) { best = y; br = nb; }   // strict > == first-occurrence argmax
        }
        br_l[slb] = br;
        float m = lg[0];
        #pragma unroll
        for (int nb = 1; nb < 8; ++nb) m = fmaxf(m, lg[nb]);
        float se = 0.f;
        #pragma unroll
        for (int nb = 0; nb < 8; ++nb) se += __expf(lg[nb] - m);
        float lse = __logf(se);
        float lp = (lg[br] - m) - lse;
        float ent = 0.f;
        #pragma unroll
        for (int nb = 0; nb < 8; ++nb) {
          float lpi = (lg[nb] - m) - lse;
          ent -= __expf(lpi) * lpi;
        }
        size_t row = (size_t)(b0 + slb) * LSTEPS + t;
        out[row]        = (float)br;
        out[BL + row]   = lp;
        out[2*BL + row] = ent;
        out[3*BL + row] = __expf(lp);
      }
    }
    BAR_LGKM();   // (E) br_l visible for next step's combine

    float* tmp = hcur; hcur = hnxt; hnxt = tmp;
  }
}

extern "C" void kernel_launch(void* const* d_in, const int* in_sizes, int n_in,
                              void* d_out, int out_size, void* d_ws, size_t ws_size,
                              hipStream_t stream) {
  const int*   class_ids = (const int*)d_in[0];
  const float* gumbel_u  = (const float*)d_in[1];
  const float* g_emb     = (const float*)d_in[2];
  const float* w_emb     = (const float*)d_in[3];
  const float* w_soft    = (const float*)d_in[4];
  const float* w_ih      = (const float*)d_in[5];
  const float* w_hh      = (const float*)d_in[6];
  const float* b_ih      = (const float*)d_in[7];
  const float* b_hh      = (const float*)d_in[8];
  float* out = (float*)d_out;
  float* ws  = (float*)d_ws;
  int B = in_sizes[0];

  hipLaunchKernelGGL(setup_kernel, dim3(256), dim3(256), 0, stream,
                     w_emb, w_ih, w_hh, b_ih, b_hh, ws);
  hipLaunchKernelGGL(ctrl_kernel, dim3(B / TILE_B), dim3(256), 0, stream,
                     class_ids, gumbel_u, g_emb, w_soft, ws, out, B);
}